// Round 8
// baseline (221.100 us; speedup 1.0000x reference)
//
#include <hip/hip_runtime.h>

#define N_NODES 100000
#define DIM 128
#define NBIN 391      // dest bins of 256 nodes: bin = r >> 8
#define BINSZ 256
#define NCH 782       // fill chunks of 2048 edges (R12-measured-best)
#define CHUNK 2048
#define FCAP 24       // per-(chunk,bin) slots; cell mean 5.24
#define SLOTS (NBIN * FCAP)  // 9384 dwords per chunk plane
#define ENTCAP 4608   // per-bin capacity; mean 4092, +8 sigma
#define FSPB 128      // fill spill slots per chunk (never used)
#define LSPB 64       // LDS capacity-spill slots per bin (never used)
#define NFG (3 * NCH) // 2346 fused blocks: 782 fill + 1564 gemm-64 tiles

typedef __attribute__((ext_vector_type(8))) short bf16x8;
typedef __attribute__((ext_vector_type(4))) float f32x4;

__device__ __forceinline__ unsigned short f2bf(float f) {
  unsigned u = __builtin_bit_cast(unsigned, f);
  u += 0x7fff + ((u >> 16) & 1);  // RNE
  return (unsigned short)(u >> 16);
}
__device__ __forceinline__ float bfhi(unsigned u) {
  return __builtin_bit_cast(float, u & 0xffff0000u);
}
__device__ __forceinline__ float bflo(unsigned u) {
  return __builtin_bit_cast(float, u << 16);
}

// ---------------------------------------------------------------------------
// Kernel 1: FUSED fill+gemm at FILL'S occupancy (the R15 retry done right).
// Triples: blockIdx%3==0 -> fill chunk (R12/R17 body, unchanged);
// %3 in {1,2} -> 64-row gemm tile (R19 body) with INLINE per-ks W f32->bf16
// conversion (W is L2-hot 128 KB; removes Wb + wconv pre-pass and its
// ordering hazard).  Union LDS 39.1 KB -> 4 blocks/CU for BOTH roles (R15's
// failure was fill at 2/CU).  launch_bounds(256,4): gemm path peak ~107 VGPR
// (acc[4][4]=64 + bfk 16 + temps), under the 128 cap -> no R16-style spill.
// ---------------------------------------------------------------------------
union FgSh {
  struct {
    unsigned buf[SLOTS];  // 37.5 KB, layout b*FCAP + slot
    int lcnt[NBIN];
    int fsc;
  } f;                       // 39.1 KB
  unsigned short xs[64 * 136];  // 17.4 KB
};

__global__ __launch_bounds__(256, 4) void fillgemm_kernel(
    const int* __restrict__ rows, const int* __restrict__ cols,
    int* __restrict__ counts, unsigned* __restrict__ binned,
    int* __restrict__ fspillc, int2* __restrict__ fspill, int n_edges,
    const float* __restrict__ x, const float* __restrict__ W1,
    const float* __restrict__ W2, unsigned short* __restrict__ selfb,
    unsigned short* __restrict__ neigh) {
  __shared__ FgSh sh;
  const int tid = threadIdx.x;
  const int g = blockIdx.x / 3;
  const int r3 = blockIdx.x - 3 * g;

  if (r3 == 0) {
    // ===================== FILL path: chunk g (R17-exact) =====================
    const int ch = g;
    for (int i = tid; i < NBIN; i += 256) sh.f.lcnt[i] = 0;
    if (tid == 0) sh.f.fsc = 0;
    __syncthreads();

    const int e0 = ch * CHUNK + tid * 8;
    int rv[8], cv[8];
    int nval;
    if (e0 + 8 <= n_edges) {
      *(int4*)&rv[0] = *(const int4*)(rows + e0);
      *(int4*)&rv[4] = *(const int4*)(rows + e0 + 4);
      *(int4*)&cv[0] = *(const int4*)(cols + e0);
      *(int4*)&cv[4] = *(const int4*)(cols + e0 + 4);
      nval = 8;
    } else {
      nval = 0;
      for (int k = 0; k < 8; ++k)
        if (e0 + k < n_edges) {
          rv[nval] = rows[e0 + k];
          cv[nval] = cols[e0 + k];
          ++nval;
        }
    }
    for (int k = 0; k < nval; ++k) {
      const int r = rv[k];
      const int b = r >> 8;
      const unsigned payload = ((unsigned)(r & 255) << 17) | (unsigned)cv[k];
      const int slot = atomicAdd(&sh.f.lcnt[b], 1);
      if (slot < FCAP) {
        sh.f.buf[b * FCAP + slot] = payload;
      } else {  // ~never
        const int sp = atomicAdd(&sh.f.fsc, 1);
        if (sp < FSPB) fspill[ch * FSPB + sp] = make_int2(r, cv[k]);
      }
    }
    __syncthreads();

    // compact coalesced flush: only live quads (reader guards with counts)
    unsigned* dst = binned + (size_t)ch * SLOTS;
    for (int u = tid; u < SLOTS / 4; u += 256) {
      const int b = u / 6;  // FCAP/4 = 6 quads per bin
      const int q = u - b * 6;
      const int cnt = min(sh.f.lcnt[b], FCAP);
      if (4 * q < cnt)
        *(uint4*)(dst + 4 * u) = *(const uint4*)&sh.f.buf[4 * u];
    }
    for (int b = tid; b < NBIN; b += 256)
      counts[(size_t)ch * NBIN + b] = min(sh.f.lcnt[b], FCAP);
    if (tid == 0) fspillc[ch] = min(sh.f.fsc, FSPB);  // ALWAYS written
  } else {
    // ============== GEMM path: 64-row tile t (R19 body, inline W) ==============
    const int t = g * 2 + (r3 - 1);  // [0, 1564)
    const int lane = tid & 63;
    const int w = tid >> 6;
    const int nb = t * 64;
    const int quad = lane >> 4;
    const int l15 = lane & 15;

    // ---- stage A: 64 rows x 128 dims fp32 -> bf16 LDS ----
    {
      float4 av[8];
#pragma unroll
      for (int it = 0; it < 8; ++it) {
        const int v = tid + it * 256;
        const int m = v >> 5, q = v & 31;
        av[it] = (nb + m < N_NODES)
                     ? *(const float4*)(x + (size_t)(nb + m) * DIM + 4 * q)
                     : make_float4(0.f, 0.f, 0.f, 0.f);
      }
#pragma unroll
      for (int it = 0; it < 8; ++it) {
        const int v = tid + it * 256;
        const int m = v >> 5, q = v & 31;
        const unsigned lo =
            (unsigned)f2bf(av[it].x) | ((unsigned)f2bf(av[it].y) << 16);
        const unsigned hi =
            (unsigned)f2bf(av[it].z) | ((unsigned)f2bf(av[it].w) << 16);
        *(uint2*)&sh.xs[m * 136 + 4 * q] = make_uint2(lo, hi);
      }
    }
    __syncthreads();

    f32x4 acc[4][4];
#pragma unroll
    for (int mt = 0; mt < 4; ++mt)
#pragma unroll
      for (int nt = 0; nt < 4; ++nt) acc[mt][nt] = (f32x4){0.f, 0.f, 0.f, 0.f};

#pragma unroll
    for (int ks = 0; ks < 4; ++ks) {
      bf16x8 bfk[4];  // per-ks B fragments, converted inline from f32 W
#pragma unroll
      for (int nt = 0; nt < 4; ++nt) {
        const int j = w * 64 + nt * 16 + l15;  // [0,256): W1 rows then W2 rows
        const float* Wrow =
            (j < 128) ? (W1 + (size_t)j * DIM) : (W2 + (size_t)(j - 128) * DIM);
        const float4 a = *(const float4*)(Wrow + ks * 32 + quad * 8);
        const float4 b = *(const float4*)(Wrow + ks * 32 + quad * 8 + 4);
        union {
          bf16x8 v;
          unsigned short u[8];
        } tmp;
        tmp.u[0] = f2bf(a.x);
        tmp.u[1] = f2bf(a.y);
        tmp.u[2] = f2bf(a.z);
        tmp.u[3] = f2bf(a.w);
        tmp.u[4] = f2bf(b.x);
        tmp.u[5] = f2bf(b.y);
        tmp.u[6] = f2bf(b.z);
        tmp.u[7] = f2bf(b.w);
        bfk[nt] = tmp.v;
      }
#pragma unroll
      for (int mt = 0; mt < 4; ++mt) {
        const bf16x8 afrag =
            *(const bf16x8*)&sh.xs[(mt * 16 + l15) * 136 + ks * 32 + quad * 8];
#pragma unroll
        for (int nt = 0; nt < 4; ++nt)
          acc[mt][nt] = __builtin_amdgcn_mfma_f32_16x16x32_bf16(
              afrag, bfk[nt], acc[mt][nt], 0, 0, 0);
      }
    }

#pragma unroll
    for (int h = 0; h < 2; ++h) {
      __syncthreads();
      if ((w >> 1) == h) {
#pragma unroll
        for (int mt = 0; mt < 4; ++mt)
#pragma unroll
          for (int nt = 0; nt < 4; ++nt) {
            const int col = (w & 1) * 64 + nt * 16 + l15;
#pragma unroll
            for (int r = 0; r < 4; ++r)
              sh.xs[(mt * 16 + quad * 4 + r) * 136 + col] =
                  f2bf(acc[mt][nt][r]);
          }
      }
      __syncthreads();
      unsigned short* dst = h ? neigh : selfb;
#pragma unroll
      for (int it = 0; it < 4; ++it) {
        const int v = it * 256 + tid;
        const int row = v >> 4, q = v & 15;  // 64 rows x 16 uint4
        if (nb + row < N_NODES)
          *(uint4*)(dst + (size_t)(nb + row) * DIM + 8 * q) =
              *(const uint4*)&sh.xs[row * 136 + 8 * q];
      }
    }
  }
}

// ---------------------------------------------------------------------------
// Kernel 2: FUSED sort+agg — R17-EXACT (frozen).  The agg gather sits at the
// random-256B service wall (~2.6 TB/s effective, 210 MB FETCH): R13
// falsified concurrency tuning, R18 falsified XCD locality partitioning.
// ---------------------------------------------------------------------------
__global__ __launch_bounds__(1024, 8) void sortagg_kernel(
    const int* __restrict__ counts, const unsigned* __restrict__ binned,
    const unsigned short* __restrict__ neigh,
    const unsigned short* __restrict__ selfb,
    const int* __restrict__ fspillc, const int2* __restrict__ fspill,
    float* __restrict__ out) {
  __shared__ int segc[NCH];        // 3.1 KB
  __shared__ int ssa[NCH];         // 3.1 KB (in-place inclusive scan)
  __shared__ unsigned entbuf[ENTCAP];  // 18.4 KB
  __shared__ int outb[ENTCAP];         // 18.4 KB
  __shared__ int hist[BINSZ], hsa[BINSZ], cur[BINSZ];  // 3 KB
  __shared__ unsigned lspill[LSPB];
  __shared__ int lsc, tot, hasf;

  const int tid = threadIdx.x;
  const int bin = blockIdx.x;

  if (tid == 0) {
    lsc = 0;
    hasf = 0;
  }
  if (tid < BINSZ) hist[tid] = 0;
  for (int i = tid; i < NCH; i += 1024) {
    const int c = counts[(size_t)i * NBIN + bin];
    segc[i] = c;
    ssa[i] = c;
    if (fspillc[i]) atomicOr(&hasf, 1);
  }
  __syncthreads();

  // in-place Hillis-Steele inclusive scan over NCH (one elem per thread)
  for (int off = 1; off < NCH; off <<= 1) {
    int add = 0;
    if (tid < NCH && tid >= off) add = ssa[tid - off];
    __syncthreads();
    if (tid < NCH && tid >= off) ssa[tid] += add;
    __syncthreads();
  }
  if (tid == 0) tot = min(ssa[NCH - 1], ENTCAP);

  // compaction: 782 segs, only live quads (writer flushed only those)
  const unsigned* bbase = binned + (size_t)bin * FCAP;
  for (int u = tid; u < NCH * (FCAP / 4); u += 1024) {
    const int ch = u / 6;
    const int q = u - ch * 6;
    const int cnt = segc[ch];
    if (4 * q < cnt) {
      uint4 v4 = *(const uint4*)(bbase + (size_t)ch * SLOTS + 4 * q);
      const int base = ssa[ch] - cnt;  // exclusive prefix
      const unsigned vals[4] = {v4.x, v4.y, v4.z, v4.w};
#pragma unroll
      for (int j = 0; j < 4; ++j) {
        const int slot = 4 * q + j;
        if (slot < cnt) {
          const int pos = base + slot;
          if (pos < ENTCAP) {
            entbuf[pos] = vals[j];
          } else {  // ~never: bin total exceeded ENTCAP
            const int sp = atomicAdd(&lsc, 1);
            if (sp < LSPB) lspill[sp] = vals[j];
          }
        }
      }
    }
  }
  __syncthreads();

  // append fill-spill entries for this bin (never taken in practice)
  if (hasf) {
    for (int bi = tid; bi < NCH; bi += 1024) {
      const int n = min(fspillc[bi], FSPB);
      for (int i = 0; i < n; ++i) {
        const int2 e = fspill[bi * FSPB + i];
        if ((e.x >> 8) == bin) {
          const unsigned pay = ((unsigned)(e.x & 255) << 17) | (unsigned)e.y;
          const int pos = atomicAdd(&tot, 1);
          if (pos < ENTCAP) {
            entbuf[pos] = pay;
          } else {
            const int sp = atomicAdd(&lsc, 1);
            if (sp < LSPB) lspill[sp] = pay;
          }
        }
      }
    }
    __syncthreads();
  }
  const int total = min(tot, ENTCAP);

  // histogram over dest-node-within-bin
  for (int i = tid; i < total; i += 1024)
    atomicAdd(&hist[entbuf[i] >> 17], 1);
  __syncthreads();
  if (tid < BINSZ) hsa[tid] = hist[tid];
  __syncthreads();
  for (int off = 1; off < BINSZ; off <<= 1) {
    int add = 0;
    if (tid < BINSZ && tid >= off) add = hsa[tid - off];
    __syncthreads();
    if (tid < BINSZ && tid >= off) hsa[tid] += add;
    __syncthreads();
  }
  if (tid < BINSZ) cur[tid] = hsa[tid] - hist[tid];
  __syncthreads();

  // scatter into per-node segments
  for (int i = tid; i < total; i += 1024) {
    const unsigned p = entbuf[i];
    const int pos = atomicAdd(&cur[p >> 17], 1);
    outb[pos] = (int)(p & 0x1FFFFu);
  }
  __syncthreads();

  // ================= agg phase: 16 waves x 16 nodes =================
  const int l = tid & 63;
  const int wv = tid >> 6;
  const unsigned* ng = (const unsigned*)neigh;
  const unsigned* sfp = (const unsigned*)selfb;
  const int nspill = min(lsc, LSPB);

  for (int k = 0; k < 16; ++k) {
    const int nl = wv * 16 + k;
    const int node = (bin << 8) | nl;
    if (node >= N_NODES) break;  // node monotone in k
    const int deg = hist[nl];
    const int start = hsa[nl] - hist[nl];
    const unsigned s = sfp[(size_t)node * 64 + l];

    float ax = 0.f, ay = 0.f;
    int d = 0;
    for (; d + 8 <= deg; d += 8) {
      unsigned uv[8];
#pragma unroll
      for (int j = 0; j < 8; ++j)
        uv[j] = ng[(size_t)outb[start + d + j] * 64 + l];
#pragma unroll
      for (int j = 0; j < 8; ++j) {
        ax += bflo(uv[j]);
        ay += bfhi(uv[j]);
      }
    }
    const int rem = deg - d;
    if (rem) {
      unsigned uv[8];
      const int cdup = outb[start + d];  // dup row stays in-cache
#pragma unroll
      for (int j = 0; j < 8; ++j) {
        const int ci = (j < rem) ? outb[start + d + j] : cdup;
        uv[j] = ng[(size_t)ci * 64 + l];
      }
#pragma unroll
      for (int j = 0; j < 8; ++j) {
        if (j < rem) {  // wave-uniform mask
          ax += bflo(uv[j]);
          ay += bfhi(uv[j]);
        }
      }
    }

    for (int i = 0; i < nspill; ++i) {  // 0 iterations in practice
      const unsigned p = lspill[i];
      if ((int)(p >> 17) == nl) {
        const unsigned u = ng[(size_t)(p & 0x1FFFFu) * 64 + l];
        ax += bflo(u);
        ay += bfhi(u);
      }
    }

    float2 o;
    o.x = fmaxf(bflo(s) + ax, 0.f);
    o.y = fmaxf(bfhi(s) + ay, 0.f);
    *(float2*)(out + (size_t)node * DIM + 2 * l) = o;
  }
}

extern "C" void kernel_launch(void* const* d_in, const int* in_sizes, int n_in,
                              void* d_out, int out_size, void* d_ws,
                              size_t ws_size, hipStream_t stream) {
  const float* x = (const float*)d_in[0];
  const int* edge_index = (const int*)d_in[1];  // (2,E): [0]=row(dst), [1]=col(src)
  const float* W1 = (const float*)d_in[2];
  const float* W2 = (const float*)d_in[3];
  float* out = (float*)d_out;

  const int n_edges = in_sizes[1] / 2;
  const int* rows = edge_index;
  const int* cols = edge_index + n_edges;

  // ws layout (walk kept identical for stability; several regions unused)
  char* p = (char*)d_ws;
  unsigned short* selfb = (unsigned short*)p;
  p += (size_t)N_NODES * DIM * 2;
  unsigned short* neigh = (unsigned short*)p;
  p += (size_t)N_NODES * DIM * 2;
  unsigned* binned = (unsigned*)p;
  p += (size_t)NCH * SLOTS * 4;
  int* counts = (int*)p;
  p += (size_t)NCH * NBIN * 4;
  p += (size_t)NBIN * ENTCAP * 4;   // (reserved)
  p += (size_t)N_NODES * 4;         // (reserved)
  p += (size_t)N_NODES * 4;         // (reserved)
  int* fspillc = (int*)p;
  p += 4096;
  int2* fspill = (int2*)p;
  p += (size_t)NCH * FSPB * sizeof(int2);

  fillgemm_kernel<<<NFG, 256, 0, stream>>>(rows, cols, counts, binned,
                                           fspillc, fspill, n_edges, x, W1,
                                           W2, selfb, neigh);
  sortagg_kernel<<<NBIN, 1024, 0, stream>>>(counts, binned, neigh, selfb,
                                            fspillc, fspill, out);
}

// Round 9
// 216.912 us; speedup vs baseline: 1.0193x; 1.0193x over previous
//
#include <hip/hip_runtime.h>

#define N_NODES 100000
#define DIM 128
#define NBIN 391      // dest bins of 256 nodes: bin = r >> 8
#define BINSZ 256
#define NCH 782       // fill chunks of 2048 edges (R12-measured-best)
#define CHUNK 2048
#define FCAP 24       // per-(chunk,bin) slots; cell mean 5.24
#define SLOTS (NBIN * FCAP)  // 9384 dwords per chunk plane
#define ENTCAP 4608   // per-bin capacity; mean 4092, +8 sigma
#define FSPB 128      // fill spill slots per chunk (never used)
#define LSPB 64       // LDS capacity-spill slots per bin (never used)
#define NGEMM 782     // gemm tiles of 128 nodes

typedef __attribute__((ext_vector_type(8))) short bf16x8;
typedef __attribute__((ext_vector_type(4))) float f32x4;
typedef __attribute__((ext_vector_type(2))) float f32x2;

__device__ __forceinline__ unsigned short f2bf(float f) {
  unsigned u = __builtin_bit_cast(unsigned, f);
  u += 0x7fff + ((u >> 16) & 1);  // RNE
  return (unsigned short)(u >> 16);
}
__device__ __forceinline__ float bfhi(unsigned u) {
  return __builtin_bit_cast(float, u & 0xffff0000u);
}
__device__ __forceinline__ float bflo(unsigned u) {
  return __builtin_bit_cast(float, u << 16);
}

// ---------------------------------------------------------------------------
// Kernel 1: LDS-staged binning (R12-measured-best) + compact flush (R17) +
// 32 trailing blocks pre-convert W fp32->bf16 into Wb.  R17-EXACT.
// ---------------------------------------------------------------------------
__global__ __launch_bounds__(256, 4) void fill_kernel(
    const int* __restrict__ rows, const int* __restrict__ cols,
    int* __restrict__ counts, unsigned* __restrict__ binned,
    int* __restrict__ fspillc, int2* __restrict__ fspill, int n_edges,
    const float* __restrict__ W1, const float* __restrict__ W2,
    unsigned short* __restrict__ Wb) {
  const int tid = threadIdx.x;
  if (blockIdx.x >= NCH) {
    // -------- wconv path: 32 blocks x 256 threads = 8192 float4 --------
    const int v = (blockIdx.x - NCH) * 256 + tid;
    const int j = v >> 5, q = v & 31;
    const float* Wrow =
        (j < 128) ? (W1 + (size_t)j * DIM) : (W2 + (size_t)(j - 128) * DIM);
    const float4 val = *(const float4*)(Wrow + 4 * q);
    const unsigned lo = (unsigned)f2bf(val.x) | ((unsigned)f2bf(val.y) << 16);
    const unsigned hi = (unsigned)f2bf(val.z) | ((unsigned)f2bf(val.w) << 16);
    *(uint2*)(Wb + (size_t)j * DIM + 4 * q) = make_uint2(lo, hi);
    return;
  }

  __shared__ unsigned buf[SLOTS];  // 37.5 KB, layout b*FCAP + slot
  __shared__ int lcnt[NBIN];
  __shared__ int fsc;
  const int ch = blockIdx.x;
  for (int i = tid; i < NBIN; i += 256) lcnt[i] = 0;
  if (tid == 0) fsc = 0;
  __syncthreads();

  const int e0 = ch * CHUNK + tid * 8;
  int rv[8], cv[8];
  int nval;
  if (e0 + 8 <= n_edges) {
    *(int4*)&rv[0] = *(const int4*)(rows + e0);
    *(int4*)&rv[4] = *(const int4*)(rows + e0 + 4);
    *(int4*)&cv[0] = *(const int4*)(cols + e0);
    *(int4*)&cv[4] = *(const int4*)(cols + e0 + 4);
    nval = 8;
  } else {
    nval = 0;
    for (int k = 0; k < 8; ++k)
      if (e0 + k < n_edges) {
        rv[nval] = rows[e0 + k];
        cv[nval] = cols[e0 + k];
        ++nval;
      }
  }
  for (int k = 0; k < nval; ++k) {
    const int r = rv[k];
    const int b = r >> 8;
    const unsigned payload = ((unsigned)(r & 255) << 17) | (unsigned)cv[k];
    const int slot = atomicAdd(&lcnt[b], 1);
    if (slot < FCAP) {
      buf[b * FCAP + slot] = payload;
    } else {  // ~never
      const int sp = atomicAdd(&fsc, 1);
      if (sp < FSPB) fspill[ch * FSPB + sp] = make_int2(r, cv[k]);
    }
  }
  __syncthreads();

  // compact coalesced flush: only live quads (reader guards with counts)
  unsigned* dst = binned + (size_t)ch * SLOTS;
  for (int u = tid; u < SLOTS / 4; u += 256) {
    const int b = u / 6;  // FCAP/4 = 6 quads per bin
    const int q = u - b * 6;
    const int cnt = min(lcnt[b], FCAP);
    if (4 * q < cnt)
      *(uint4*)(dst + 4 * u) = *(const uint4*)&buf[4 * u];
  }
  for (int b = tid; b < NBIN; b += 256)
    counts[(size_t)ch * NBIN + b] = min(lcnt[b], FCAP);
  if (tid == 0) fspillc[ch] = min(fsc, FSPB);  // ALWAYS written
}

// ---------------------------------------------------------------------------
// Kernel 2: GEMM — R14-EXACT.  launch_bounds(256,2): R16 proved (256,3)
// spills acc[8][4] (VGPR_Count 84, 150 MB scratch writes).  Do not raise.
// R19 proved 64-row tiles at 3/CU are neutral: gemm is NOT occupancy-bound.
// ---------------------------------------------------------------------------
__global__ __launch_bounds__(256, 2) void gemm_kernel(
    const float* __restrict__ x, const unsigned short* __restrict__ Wb,
    unsigned short* __restrict__ selfb, unsigned short* __restrict__ neigh) {
  __shared__ unsigned short xs[128 * 136];  // 34.8 KB
  const int tid = threadIdx.x;
  const int t = blockIdx.x;
  const int lane = tid & 63;
  const int w = tid >> 6;
  const int nb = t * 128;
  const int quad = lane >> 4;
  const int l15 = lane & 15;

  bf16x8 bfrag[4][4];
#pragma unroll
  for (int nt = 0; nt < 4; ++nt) {
    const int j = w * 64 + nt * 16 + l15;
#pragma unroll
    for (int ks = 0; ks < 4; ++ks)
      bfrag[nt][ks] =
          *(const bf16x8*)(Wb + (size_t)j * DIM + ks * 32 + quad * 8);
  }

#pragma unroll
  for (int half = 0; half < 2; ++half) {
    float4 av[8];
#pragma unroll
    for (int it = 0; it < 8; ++it) {
      const int v = tid + (half * 8 + it) * 256;
      const int m = v >> 5, q = v & 31;
      av[it] = (nb + m < N_NODES)
                   ? *(const float4*)(x + (size_t)(nb + m) * DIM + 4 * q)
                   : make_float4(0.f, 0.f, 0.f, 0.f);
    }
#pragma unroll
    for (int it = 0; it < 8; ++it) {
      const int v = tid + (half * 8 + it) * 256;
      const int m = v >> 5, q = v & 31;
      const unsigned lo =
          (unsigned)f2bf(av[it].x) | ((unsigned)f2bf(av[it].y) << 16);
      const unsigned hi =
          (unsigned)f2bf(av[it].z) | ((unsigned)f2bf(av[it].w) << 16);
      *(uint2*)&xs[m * 136 + 4 * q] = make_uint2(lo, hi);
    }
  }
  __syncthreads();

  f32x4 acc[8][4];
#pragma unroll
  for (int mt = 0; mt < 8; ++mt)
#pragma unroll
    for (int nt = 0; nt < 4; ++nt) acc[mt][nt] = (f32x4){0.f, 0.f, 0.f, 0.f};

#pragma unroll
  for (int ks = 0; ks < 4; ++ks) {
#pragma unroll
    for (int mt = 0; mt < 8; ++mt) {
      const bf16x8 afrag =
          *(const bf16x8*)&xs[(mt * 16 + l15) * 136 + ks * 32 + quad * 8];
#pragma unroll
      for (int nt = 0; nt < 4; ++nt)
        acc[mt][nt] = __builtin_amdgcn_mfma_f32_16x16x32_bf16(
            afrag, bfrag[nt][ks], acc[mt][nt], 0, 0, 0);
    }
  }

#pragma unroll
  for (int h = 0; h < 2; ++h) {
    __syncthreads();
    if ((w >> 1) == h) {
#pragma unroll
      for (int mt = 0; mt < 8; ++mt)
#pragma unroll
        for (int nt = 0; nt < 4; ++nt) {
          const int col = (w & 1) * 64 + nt * 16 + l15;
#pragma unroll
          for (int r = 0; r < 4; ++r)
            xs[(mt * 16 + quad * 4 + r) * 136 + col] = f2bf(acc[mt][nt][r]);
        }
    }
    __syncthreads();
    unsigned short* dst = h ? neigh : selfb;
#pragma unroll
    for (int it = 0; it < 8; ++it) {
      const int v = it * 256 + tid;
      const int row = v >> 4, q = v & 15;
      if (nb + row < N_NODES)
        *(uint4*)(dst + (size_t)(nb + row) * DIM + 8 * q) =
            *(const uint4*)&xs[row * 136 + 8 * q];
    }
  }
}

// ---------------------------------------------------------------------------
// Kernel 3: FUSED sort+agg — R17 body + NON-TEMPORAL hints on the two
// single-use streams (selfb load, out store; 76.8 MB touched exactly once):
// keeps them from evicting neigh lines in the 4 MB per-XCD L2s.  The gather
// sits at the pattern wall (~176 MB neigh replication at ~2.6 TB/s service):
// R13 falsified concurrency, R18 falsified XCD partitioning, R17's read
// guard proved binned/counts reads are already near-line-efficient.
// ---------------------------------------------------------------------------
__global__ __launch_bounds__(1024, 8) void sortagg_kernel(
    const int* __restrict__ counts, const unsigned* __restrict__ binned,
    const unsigned short* __restrict__ neigh,
    const unsigned short* __restrict__ selfb,
    const int* __restrict__ fspillc, const int2* __restrict__ fspill,
    float* __restrict__ out) {
  __shared__ int segc[NCH];        // 3.1 KB
  __shared__ int ssa[NCH];         // 3.1 KB (in-place inclusive scan)
  __shared__ unsigned entbuf[ENTCAP];  // 18.4 KB
  __shared__ int outb[ENTCAP];         // 18.4 KB
  __shared__ int hist[BINSZ], hsa[BINSZ], cur[BINSZ];  // 3 KB
  __shared__ unsigned lspill[LSPB];
  __shared__ int lsc, tot, hasf;

  const int tid = threadIdx.x;
  const int bin = blockIdx.x;

  if (tid == 0) {
    lsc = 0;
    hasf = 0;
  }
  if (tid < BINSZ) hist[tid] = 0;
  for (int i = tid; i < NCH; i += 1024) {
    const int c = counts[(size_t)i * NBIN + bin];
    segc[i] = c;
    ssa[i] = c;
    if (fspillc[i]) atomicOr(&hasf, 1);
  }
  __syncthreads();

  // in-place Hillis-Steele inclusive scan over NCH (one elem per thread)
  for (int off = 1; off < NCH; off <<= 1) {
    int add = 0;
    if (tid < NCH && tid >= off) add = ssa[tid - off];
    __syncthreads();
    if (tid < NCH && tid >= off) ssa[tid] += add;
    __syncthreads();
  }
  if (tid == 0) tot = min(ssa[NCH - 1], ENTCAP);

  // compaction: 782 segs, only live quads (writer flushed only those)
  const unsigned* bbase = binned + (size_t)bin * FCAP;
  for (int u = tid; u < NCH * (FCAP / 4); u += 1024) {
    const int ch = u / 6;
    const int q = u - ch * 6;
    const int cnt = segc[ch];
    if (4 * q < cnt) {
      uint4 v4 = *(const uint4*)(bbase + (size_t)ch * SLOTS + 4 * q);
      const int base = ssa[ch] - cnt;  // exclusive prefix
      const unsigned vals[4] = {v4.x, v4.y, v4.z, v4.w};
#pragma unroll
      for (int j = 0; j < 4; ++j) {
        const int slot = 4 * q + j;
        if (slot < cnt) {
          const int pos = base + slot;
          if (pos < ENTCAP) {
            entbuf[pos] = vals[j];
          } else {  // ~never: bin total exceeded ENTCAP
            const int sp = atomicAdd(&lsc, 1);
            if (sp < LSPB) lspill[sp] = vals[j];
          }
        }
      }
    }
  }
  __syncthreads();

  // append fill-spill entries for this bin (never taken in practice)
  if (hasf) {
    for (int bi = tid; bi < NCH; bi += 1024) {
      const int n = min(fspillc[bi], FSPB);
      for (int i = 0; i < n; ++i) {
        const int2 e = fspill[bi * FSPB + i];
        if ((e.x >> 8) == bin) {
          const unsigned pay = ((unsigned)(e.x & 255) << 17) | (unsigned)e.y;
          const int pos = atomicAdd(&tot, 1);
          if (pos < ENTCAP) {
            entbuf[pos] = pay;
          } else {
            const int sp = atomicAdd(&lsc, 1);
            if (sp < LSPB) lspill[sp] = pay;
          }
        }
      }
    }
    __syncthreads();
  }
  const int total = min(tot, ENTCAP);

  // histogram over dest-node-within-bin
  for (int i = tid; i < total; i += 1024)
    atomicAdd(&hist[entbuf[i] >> 17], 1);
  __syncthreads();
  if (tid < BINSZ) hsa[tid] = hist[tid];
  __syncthreads();
  for (int off = 1; off < BINSZ; off <<= 1) {
    int add = 0;
    if (tid < BINSZ && tid >= off) add = hsa[tid - off];
    __syncthreads();
    if (tid < BINSZ && tid >= off) hsa[tid] += add;
    __syncthreads();
  }
  if (tid < BINSZ) cur[tid] = hsa[tid] - hist[tid];
  __syncthreads();

  // scatter into per-node segments
  for (int i = tid; i < total; i += 1024) {
    const unsigned p = entbuf[i];
    const int pos = atomicAdd(&cur[p >> 17], 1);
    outb[pos] = (int)(p & 0x1FFFFu);
  }
  __syncthreads();

  // ================= agg phase: 16 waves x 16 nodes =================
  const int l = tid & 63;
  const int wv = tid >> 6;
  const unsigned* ng = (const unsigned*)neigh;
  const unsigned* sfp = (const unsigned*)selfb;
  const int nspill = min(lsc, LSPB);

  for (int k = 0; k < 16; ++k) {
    const int nl = wv * 16 + k;
    const int node = (bin << 8) | nl;
    if (node >= N_NODES) break;  // node monotone in k
    const int deg = hist[nl];
    const int start = hsa[nl] - hist[nl];
    const unsigned s =
        __builtin_nontemporal_load(sfp + (size_t)node * 64 + l);  // once-only

    float ax = 0.f, ay = 0.f;
    int d = 0;
    for (; d + 8 <= deg; d += 8) {
      unsigned uv[8];
#pragma unroll
      for (int j = 0; j < 8; ++j)
        uv[j] = ng[(size_t)outb[start + d + j] * 64 + l];
#pragma unroll
      for (int j = 0; j < 8; ++j) {
        ax += bflo(uv[j]);
        ay += bfhi(uv[j]);
      }
    }
    const int rem = deg - d;
    if (rem) {
      unsigned uv[8];
      const int cdup = outb[start + d];  // dup row stays in-cache
#pragma unroll
      for (int j = 0; j < 8; ++j) {
        const int ci = (j < rem) ? outb[start + d + j] : cdup;
        uv[j] = ng[(size_t)ci * 64 + l];
      }
#pragma unroll
      for (int j = 0; j < 8; ++j) {
        if (j < rem) {  // wave-uniform mask
          ax += bflo(uv[j]);
          ay += bfhi(uv[j]);
        }
      }
    }

    for (int i = 0; i < nspill; ++i) {  // 0 iterations in practice
      const unsigned p = lspill[i];
      if ((int)(p >> 17) == nl) {
        const unsigned u = ng[(size_t)(p & 0x1FFFFu) * 64 + l];
        ax += bflo(u);
        ay += bfhi(u);
      }
    }

    f32x2 o;
    o.x = fmaxf(bflo(s) + ax, 0.f);
    o.y = fmaxf(bfhi(s) + ay, 0.f);
    __builtin_nontemporal_store(
        o, (f32x2*)(out + (size_t)node * DIM) + l);  // once-only stream
  }
}

extern "C" void kernel_launch(void* const* d_in, const int* in_sizes, int n_in,
                              void* d_out, int out_size, void* d_ws,
                              size_t ws_size, hipStream_t stream) {
  const float* x = (const float*)d_in[0];
  const int* edge_index = (const int*)d_in[1];  // (2,E): [0]=row(dst), [1]=col(src)
  const float* W1 = (const float*)d_in[2];
  const float* W2 = (const float*)d_in[3];
  float* out = (float*)d_out;

  const int n_edges = in_sizes[1] / 2;
  const int* rows = edge_index;
  const int* cols = edge_index + n_edges;

  // ws layout (walk kept identical to R12 for stability; several regions
  // unused but reserved)
  char* p = (char*)d_ws;
  unsigned short* selfb = (unsigned short*)p;
  p += (size_t)N_NODES * DIM * 2;
  unsigned short* neigh = (unsigned short*)p;
  p += (size_t)N_NODES * DIM * 2;
  unsigned* binned = (unsigned*)p;
  p += (size_t)NCH * SLOTS * 4;
  int* counts = (int*)p;
  p += (size_t)NCH * NBIN * 4;
  p += (size_t)NBIN * ENTCAP * 4;   // (reserved)
  p += (size_t)N_NODES * 4;         // (reserved)
  p += (size_t)N_NODES * 4;         // (reserved)
  int* fspillc = (int*)p;
  p += 4096;
  int2* fspill = (int2*)p;
  p += (size_t)NCH * FSPB * sizeof(int2);
  p += 4096;                        // (reserved)
  p += (size_t)NBIN * 256 * sizeof(int2);  // (reserved)
  unsigned short* Wb = (unsigned short*)p;  // 64 KB

  fill_kernel<<<NCH + 32, 256, 0, stream>>>(rows, cols, counts, binned,
                                            fspillc, fspill, n_edges, W1, W2,
                                            Wb);
  gemm_kernel<<<NGEMM, 256, 0, stream>>>(x, Wb, selfb, neigh);
  sortagg_kernel<<<NBIN, 1024, 0, stream>>>(counts, binned, neigh, selfb,
                                            fspillc, fspill, out);
}